// Round 6
// baseline (487.153 us; speedup 1.0000x reference)
//
#include <hip/hip_runtime.h>
#include <hip/hip_bf16.h>
#include <cstdint>
#include <cstddef>

// Problem constants
#define NTOK 8192   // N
#define NHID 1024   // hidden == n_spins

typedef __attribute__((ext_vector_type(8))) __bf16 bf16x8;
typedef __attribute__((ext_vector_type(4))) float f32x4;

__device__ __forceinline__ unsigned short f2bf(float f) {
    union { float f; unsigned u; } v; v.f = f;
    unsigned r = v.u + 0x7FFF + ((v.u >> 16) & 1);   // RNE
    return (unsigned short)(r >> 16);
}

__device__ __forceinline__ float bf2f(unsigned short u) {
    union { unsigned u; float f; } v; v.u = ((unsigned)u) << 16;
    return v.f;
}

__device__ __forceinline__ void async_copy16(const void* gsrc, void* ldsdst) {
    __builtin_amdgcn_global_load_lds(
        (const __attribute__((address_space(1))) unsigned int*)gsrc,
        (__attribute__((address_space(3))) unsigned int*)ldsdst,
        16, 0, 0);
}

__device__ __forceinline__ void read_frags(
    const unsigned short* __restrict__ As, const unsigned short* __restrict__ Bs,
    int wm, int wn, int fr, int pc, bf16x8 (&a)[8], bf16x8 (&b)[4])
{
#pragma unroll
    for (int i = 0; i < 8; ++i) a[i] = *(const bf16x8*)&As[(wm + i * 16 + fr) * 64 + pc];
#pragma unroll
    for (int j = 0; j < 4; ++j) b[j] = *(const bf16x8*)&Bs[(wn + j * 16 + fr) * 64 + pc];
}

__device__ __forceinline__ void mfma32(
    const bf16x8 (&a)[8], const bf16x8 (&b)[4], f32x4 (&acc)[8][4])
{
    __builtin_amdgcn_s_setprio(1);
#pragma unroll
    for (int i = 0; i < 8; ++i)
#pragma unroll
        for (int j = 0; j < 4; ++j)
            acc[i][j] = __builtin_amdgcn_mfma_f32_16x16x32_bf16(
                a[i], b[j], acc[i][j], 0, 0, 0);
    __builtin_amdgcn_s_setprio(0);
}

// ---------------------------------------------------------------------------
// R13: gemm_sq2 = R12 geometry (256x256, per-wave 128x64, high LDS intensity)
// + R11 cross-phase REGISTER pipeline. R12 post-mortem: per-CU accounting
// shows MFMA pipe (~2484 cyc/tile) and LDS pipe (~2800 cyc/tile) fully
// SERIALIZED by lockstep read-burst/MFMA-burst alternation (observed 6375
// cyc/tile ~= sum + slack, MfmaUtil 35%). Fix: two fragment sets; each 32-MFMA
// burst overlaps the 12-ds_read issue of the other half.
//   half A: {12 ds_read ks1(cur) || stageB(t+1->nb)} -> sched_barrier ->
//           MFMA(SET-P) -> lgkmcnt(0) -> barrier -> stageA(t+2->cb) ->
//           vmcnt(4) -> barrier
//   half B: {12 ds_read ks0 of NEXT tile (nb)} -> sched_barrier ->
//           MFMA(SET-Q)
// Ledger: tile-t start outstanding = A(t+1). half-A adds B(t+1); mid adds
// A(t+2) -> vmcnt(4) drains A(t+1),B(t+1) exactly; half-B reads nb (landed).
// lgkmcnt(0)+barrier before stageA protects ds_read vs DMA overwrite of cb.
// half-B reads touch only nb; the buffer overwritten next (cb) is never read
// between its last lgkm'd read and the next mid barrier. Requires nt >= 2.
// Same R4-verified XOR-swizzle staging/read pair + epilogue map.
// ---------------------------------------------------------------------------
template <int EPI, bool SWAP>
__global__ __launch_bounds__(512, 2) void gemm_sq2(
    const unsigned short* __restrict__ A,
    const unsigned short* __restrict__ B,
    void* __restrict__ C,
    const float* __restrict__ bias,
    float* __restrict__ zsum,
    float scale, int M, int N, int K, int lda, int ldb)
{
    // 2 x (A[256][64] | B[256][64]) bf16; A at +0 (16384 ush), B at +16384.
    __shared__ __attribute__((aligned(16))) unsigned short lds[2][32768];

    const int tid  = threadIdx.x;
    const int wave = tid >> 6;          // 0..7
    const int lane = tid & 63;
    const int bm = (SWAP ? blockIdx.x : blockIdx.y) * 256;
    const int bn = (SWAP ? blockIdx.y : blockIdx.x) * 256;
    const size_t ldaz = (size_t)lda;
    const size_t ldbz = (size_t)ldb;

    const int srow = lane >> 3;
    const int scol = ((lane & 7) ^ srow) * 8;
    const unsigned short* Ag[4];
    const unsigned short* Bg[4];
    int off[4];
#pragma unroll
    for (int t = 0; t < 4; ++t) {
        int r = (wave * 4 + t) * 8 + srow;
        Ag[t] = A + (size_t)(bm + r) * ldaz + scol;
        Bg[t] = B + (size_t)(bn + r) * ldbz + scol;
        off[t] = (wave * 4 + t) * 512;   // wave-uniform; HW adds lane*16B
    }

    // per-wave output placement: 2 M-waves x 4 N-waves, each 128x64
    const int wm = (wave >> 2) * 128;
    const int wn = (wave & 3) * 64;
    const int fr = lane & 15;
    const int frl = fr & 7;
    const int q = lane >> 4;

    const int pc0 = (q ^ frl) * 8;           // swizzled chunk, ks=0
    const int pc1 = ((4 + q) ^ frl) * 8;     // swizzled chunk, ks=1

    f32x4 acc[8][4] = {};

    const int nt = K >> 6;             // BK=64 tiles; requires nt >= 2

    auto stageA = [&](int s) {
#pragma unroll
        for (int t = 0; t < 4; ++t) { async_copy16(Ag[t], &lds[s][off[t]]); Ag[t] += 64; }
    };
    auto stageB = [&](int s) {
#pragma unroll
        for (int t = 0; t < 4; ++t) { async_copy16(Bg[t], &lds[s][16384 + off[t]]); Bg[t] += 64; }
    };

    // prologue: tile0 -> buf0 (A+B), A of tile1 -> buf1; wait tile0 only.
    stageA(0);
    stageB(0);
    stageA(1);
    asm volatile("s_waitcnt vmcnt(4)" ::: "memory");
    asm volatile("s_barrier" ::: "memory");

    bf16x8 aP[8], bP[4];   // SET-P: ks0 fragments of the current tile
    bf16x8 aQ[8], bQ[4];   // SET-Q: ks1 fragments of the current tile
    read_frags(&lds[0][0], &lds[0][16384], wm, wn, fr, pc0, aP, bP);

    for (int t = 0; t < nt; ++t) {
        const int cb = t & 1;
        const int nb = cb ^ 1;
        const unsigned short* As = &lds[cb][0];
        const unsigned short* Bs = &lds[cb][16384];

        // ===== half A: issue ks1 reads + stageB(t+1); MFMA SET-P (ks0) =====
        if (t + 1 < nt) stageB(nb);
        read_frags(As, Bs, wm, wn, fr, pc1, aQ, bQ);
        __builtin_amdgcn_sched_barrier(0);
        mfma32(aP, bP, acc);
        // own ks1 reads complete before any wave's stageA overwrites cb.A
        asm volatile("s_waitcnt lgkmcnt(0)" ::: "memory");
        asm volatile("s_barrier" ::: "memory");
        if (t + 2 < nt) stageA(cb);
        if (t < nt - 2) asm volatile("s_waitcnt vmcnt(4)" ::: "memory");
        else            asm volatile("s_waitcnt vmcnt(0)" ::: "memory");
        asm volatile("s_barrier" ::: "memory");

        // ===== half B: issue ks0 reads of NEXT tile (nb); MFMA SET-Q =====
        if (t + 1 < nt)
            read_frags(&lds[nb][0], &lds[nb][16384], wm, wn, fr, pc0, aP, bP);
        __builtin_amdgcn_sched_barrier(0);
        mfma32(aQ, bQ, acc);
    }

    // epilogue: D[row=(lane>>4)*4+r][col=lane&15] per 16x16 tile (verified map)
    const int erow = q * 4;
#pragma unroll
    for (int j = 0; j < 4; ++j) {
        const int gcol = bn + wn + j * 16 + fr;
        const float bv = (EPI == 1 && bias) ? bias[gcol] : 0.0f;
        float colsum = 0.0f;
#pragma unroll
        for (int i = 0; i < 8; ++i) {
            const int grow0 = bm + wm + i * 16 + erow;
#pragma unroll
            for (int r = 0; r < 4; ++r) {
                float v;
                if (EPI == 2) {
                    // P = exp(scale*acc - 64): fixed-shift softmax numerator.
                    v = __expf(fmaf(acc[i][j][r], scale, -64.0f));
                    colsum += v;
                } else {
                    v = acc[i][j][r] * scale + bv;
                }
                size_t idx = (size_t)(grow0 + r) * N + gcol;
                if (EPI == 0) ((float*)C)[idx] = v;
                else          ((unsigned short*)C)[idx] = f2bf(v);
            }
        }
        if (EPI == 2) {
            colsum += __shfl_xor(colsum, 16, 64);
            colsum += __shfl_xor(colsum, 32, 64);
            if (q == 0) atomicAdd(&zsum[gcol], colsum);
        }
    }
}

// ---------------------------------------------------------------------------
// gemm_bt4 (R11): 256x128 tile, cross-phase register pipelining — kept for
// the GEMMs whose N is too small for 256-wide tiles (h, qkv, attn@v).
// ---------------------------------------------------------------------------
template <int EPI, bool SWAP>
__global__ __launch_bounds__(512, 2) void gemm_bt4(
    const unsigned short* __restrict__ A,
    const unsigned short* __restrict__ B,
    void* __restrict__ C,
    const float* __restrict__ bias,
    float* __restrict__ zsum,
    float scale, int M, int N, int K, int lda, int ldb)
{
    __shared__ __attribute__((aligned(16))) unsigned short lds[3][24576];

    const int tid  = threadIdx.x;
    const int wave = tid >> 6;          // 0..7
    const int lane = tid & 63;
    const int bm = (SWAP ? blockIdx.x : blockIdx.y) * 256;
    const int bn = (SWAP ? blockIdx.y : blockIdx.x) * 128;
    const size_t ldaz = (size_t)lda;
    const size_t ldbz = (size_t)ldb;

    const int srow = lane >> 3;
    const int scol = ((lane & 7) ^ srow) * 8;
    const unsigned short* Ag[4];
    const unsigned short* Bg[2];
    int Aoff[4], Boff[2];
#pragma unroll
    for (int t = 0; t < 4; ++t) {
        int r = (wave * 4 + t) * 8 + srow;
        Ag[t] = A + (size_t)(bm + r) * ldaz + scol;
        Aoff[t] = (wave * 4 + t) * 512;
    }
#pragma unroll
    for (int t = 0; t < 2; ++t) {
        int r = (wave * 2 + t) * 8 + srow;
        Bg[t] = B + (size_t)(bn + r) * ldbz + scol;
        Boff[t] = 16384 + (wave * 2 + t) * 512;
    }

    const int wm = (wave >> 1) * 64;
    const int wn = (wave & 1) * 64;
    const int fr = lane & 15;
    const int frl = fr & 7;
    const int q = lane >> 4;

    const int pc0 = (q ^ frl) * 8;
    const int pc1 = ((4 + q) ^ frl) * 8;

    f32x4 acc[4][4] = {};

    const int nt = K >> 6;

    {
        unsigned short* b0 = &lds[0][0];
        unsigned short* b1 = &lds[1][0];
#pragma unroll
        for (int u = 0; u < 4; ++u) { async_copy16(Ag[u], b0 + Aoff[u]); Ag[u] += 64; }
#pragma unroll
        for (int u = 0; u < 2; ++u) { async_copy16(Bg[u], b0 + Boff[u]); Bg[u] += 64; }
#pragma unroll
        for (int u = 0; u < 4; ++u) { async_copy16(Ag[u], b1 + Aoff[u]); Ag[u] += 64; }
#pragma unroll
        for (int u = 0; u < 2; ++u) { async_copy16(Bg[u], b1 + Boff[u]); Bg[u] += 64; }
        asm volatile("s_waitcnt vmcnt(6)" ::: "memory");
        asm volatile("s_barrier" ::: "memory");
    }

    bf16x8 a0_0, a0_1, a0_2, a0_3, b0_0, b0_1, b0_2, b0_3;   // SET0
    bf16x8 a1_0, a1_1, a1_2, a1_3, b1_0, b1_1, b1_2, b1_3;   // SET1

    {
        const unsigned short* As = &lds[0][0];
        const unsigned short* Bs = &lds[0][16384];
        a0_0 = *(const bf16x8*)&As[(wm +  0 + fr) * 64 + pc0];
        a0_1 = *(const bf16x8*)&As[(wm + 16 + fr) * 64 + pc0];
        a0_2 = *(const bf16x8*)&As[(wm + 32 + fr) * 64 + pc0];
        a0_3 = *(const bf16x8*)&As[(wm + 48 + fr) * 64 + pc0];
        b0_0 = *(const bf16x8*)&Bs[(wn +  0 + fr) * 64 + pc0];
        b0_1 = *(const bf16x8*)&Bs[(wn + 16 + fr) * 64 + pc0];
        b0_2 = *(const bf16x8*)&Bs[(wn + 32 + fr) * 64 + pc0];
        b0_3 = *(const bf16x8*)&Bs[(wn + 48 + fr) * 64 + pc0];
    }

#define MFMA16(AA0, AA1, AA2, AA3, BB0, BB1, BB2, BB3)                         \
    do {                                                                       \
        __builtin_amdgcn_s_setprio(1);                                         \
        acc[0][0] = __builtin_amdgcn_mfma_f32_16x16x32_bf16(AA0, BB0, acc[0][0], 0, 0, 0); \
        acc[0][1] = __builtin_amdgcn_mfma_f32_16x16x32_bf16(AA0, BB1, acc[0][1], 0, 0, 0); \
        acc[0][2] = __builtin_amdgcn_mfma_f32_16x16x32_bf16(AA0, BB2, acc[0][2], 0, 0, 0); \
        acc[0][3] = __builtin_amdgcn_mfma_f32_16x16x32_bf16(AA0, BB3, acc[0][3], 0, 0, 0); \
        acc[1][0] = __builtin_amdgcn_mfma_f32_16x16x32_bf16(AA1, BB0, acc[1][0], 0, 0, 0); \
        acc[1][1] = __builtin_amdgcn_mfma_f32_16x16x32_bf16(AA1, BB1, acc[1][1], 0, 0, 0); \
        acc[1][2] = __builtin_amdgcn_mfma_f32_16x16x32_bf16(AA1, BB2, acc[1][2], 0, 0, 0); \
        acc[1][3] = __builtin_amdgcn_mfma_f32_16x16x32_bf16(AA1, BB3, acc[1][3], 0, 0, 0); \
        acc[2][0] = __builtin_amdgcn_mfma_f32_16x16x32_bf16(AA2, BB0, acc[2][0], 0, 0, 0); \
        acc[2][1] = __builtin_amdgcn_mfma_f32_16x16x32_bf16(AA2, BB1, acc[2][1], 0, 0, 0); \
        acc[2][2] = __builtin_amdgcn_mfma_f32_16x16x32_bf16(AA2, BB2, acc[2][2], 0, 0, 0); \
        acc[2][3] = __builtin_amdgcn_mfma_f32_16x16x32_bf16(AA2, BB3, acc[2][3], 0, 0, 0); \
        acc[3][0] = __builtin_amdgcn_mfma_f32_16x16x32_bf16(AA3, BB0, acc[3][0], 0, 0, 0); \
        acc[3][1] = __builtin_amdgcn_mfma_f32_16x16x32_bf16(AA3, BB1, acc[3][1], 0, 0, 0); \
        acc[3][2] = __builtin_amdgcn_mfma_f32_16x16x32_bf16(AA3, BB2, acc[3][2], 0, 0, 0); \
        acc[3][3] = __builtin_amdgcn_mfma_f32_16x16x32_bf16(AA3, BB3, acc[3][3], 0, 0, 0); \
        __builtin_amdgcn_s_setprio(0);                                         \
    } while (0)

    int cb = 0;
    int sb = 2;
    for (int t = 0; t < nt; ++t) {
        const bool pf = (t + 2 < nt);
        const unsigned short* As = &lds[cb][0];
        const unsigned short* Bs = &lds[cb][16384];
        unsigned short* Sb = &lds[sb][0];
        const int nb = (cb == 2) ? 0 : cb + 1;
        const unsigned short* An = &lds[nb][0];
        const unsigned short* Bn = &lds[nb][16384];

        a1_0 = *(const bf16x8*)&As[(wm +  0 + fr) * 64 + pc1];
        a1_1 = *(const bf16x8*)&As[(wm + 16 + fr) * 64 + pc1];
        a1_2 = *(const bf16x8*)&As[(wm + 32 + fr) * 64 + pc1];
        a1_3 = *(const bf16x8*)&As[(wm + 48 + fr) * 64 + pc1];
        b1_0 = *(const bf16x8*)&Bs[(wn +  0 + fr) * 64 + pc1];
        b1_1 = *(const bf16x8*)&Bs[(wn + 16 + fr) * 64 + pc1];
        b1_2 = *(const bf16x8*)&Bs[(wn + 32 + fr) * 64 + pc1];
        b1_3 = *(const bf16x8*)&Bs[(wn + 48 + fr) * 64 + pc1];
        if (pf) {
#pragma unroll
            for (int u = 0; u < 4; ++u) { async_copy16(Ag[u], Sb + Aoff[u]); Ag[u] += 64; }
        }
        __builtin_amdgcn_sched_barrier(0);
        MFMA16(a0_0, a0_1, a0_2, a0_3, b0_0, b0_1, b0_2, b0_3);
        if (t < nt - 2) asm volatile("s_waitcnt vmcnt(4)" ::: "memory");
        else            asm volatile("s_waitcnt vmcnt(0)" ::: "memory");
        asm volatile("s_barrier" ::: "memory");

        if (t + 1 < nt) {
            a0_0 = *(const bf16x8*)&An[(wm +  0 + fr) * 64 + pc0];
            a0_1 = *(const bf16x8*)&An[(wm + 16 + fr) * 64 + pc0];
            a0_2 = *(const bf16x8*)&An[(wm + 32 + fr) * 64 + pc0];
            a0_3 = *(const bf16x8*)&An[(wm + 48 + fr) * 64 + pc0];
            b0_0 = *(const bf16x8*)&Bn[(wn +  0 + fr) * 64 + pc0];
            b0_1 = *(const bf16x8*)&Bn[(wn + 16 + fr) * 64 + pc0];
            b0_2 = *(const bf16x8*)&Bn[(wn + 32 + fr) * 64 + pc0];
            b0_3 = *(const bf16x8*)&Bn[(wn + 48 + fr) * 64 + pc0];
        }
        if (pf) {
#pragma unroll
            for (int u = 0; u < 2; ++u) { async_copy16(Bg[u], Sb + Boff[u]); Bg[u] += 64; }
        }
        __builtin_amdgcn_sched_barrier(0);
        MFMA16(a1_0, a1_1, a1_2, a1_3, b1_0, b1_1, b1_2, b1_3);
        asm volatile("s_barrier" ::: "memory");

        if (pf) sb = (sb == 2) ? 0 : sb + 1;
        cb = nb;
    }
#undef MFMA16

    const int erow = q * 4;
#pragma unroll
    for (int j = 0; j < 4; ++j) {
        const int gcol = bn + wn + j * 16 + fr;
        const float bv = (EPI == 1 && bias) ? bias[gcol] : 0.0f;
        float colsum = 0.0f;
#pragma unroll
        for (int i = 0; i < 4; ++i) {
            const int grow0 = bm + wm + i * 16 + erow;
#pragma unroll
            for (int r = 0; r < 4; ++r) {
                float v;
                if (EPI == 2) {
                    v = __expf(fmaf(acc[i][j][r], scale, -64.0f));
                    colsum += v;
                } else {
                    v = acc[i][j][r] * scale + bv;
                }
                size_t idx = (size_t)(grow0 + r) * N + gcol;
                if (EPI == 0) ((float*)C)[idx] = v;
                else          ((unsigned short*)C)[idx] = f2bf(v);
            }
        }
        if (EPI == 2) {
            colsum += __shfl_xor(colsum, 16, 64);
            colsum += __shfl_xor(colsum, 32, 64);
            if (q == 0) atomicAdd(&zsum[gcol], colsum);
        }
    }
}

// fused fp32->bf16 convert for x (n4x float4s) + 4 weight mats (n4w each)
// into xb and the CONTIGUOUS weight region wdst (wib|wq|wk|wv).
// Extra 8 trailing blocks zero-fill pz (2048 float4 = 8192 floats).
__global__ void cvt_all(const float4* __restrict__ x,
                        const float4* __restrict__ w0,
                        const float4* __restrict__ w1,
                        const float4* __restrict__ w2,
                        const float4* __restrict__ w3,
                        ushort4* __restrict__ xb,
                        ushort4* __restrict__ wdst,
                        float4* __restrict__ pz4,
                        int n4x, int n4w)
{
    int i = blockIdx.x * blockDim.x + threadIdx.x;
    int n4 = n4x + 4 * n4w;
    if (i >= n4) {
        int zi = i - n4;
        if (zi < 2048) pz4[zi] = make_float4(0.f, 0.f, 0.f, 0.f);
        return;
    }
    float4 f;
    ushort4* dst;
    if (i < n4x) {
        f = x[i]; dst = xb + i;
    } else {
        int r = i - n4x;
        int seg = r / n4w, off = r % n4w;
        const float4* src = (seg == 0) ? w0 : (seg == 1) ? w1 : (seg == 2) ? w2 : w3;
        f = src[off]; dst = wdst + r;
    }
    ushort4 o;
    o.x = f2bf(f.x); o.y = f2bf(f.y); o.z = f2bf(f.z); o.w = f2bf(f.w);
    *dst = o;
}

// vt[h][j] = v[j][h] / z[j]; v is a [NTOK, NHID] view with row stride 3072
// (the v slice of qkv). 64x64 tile via float LDS (stride 65). Both global
// sides coalesced (128B/wave segments).
__global__ __launch_bounds__(256) void transpose_scale(
    const unsigned short* __restrict__ v,
    const float* __restrict__ z,
    unsigned short* __restrict__ vt)
{
    __shared__ float lds[64 * 65];
    const int tid = threadIdx.x;
    const int j0 = blockIdx.x * 64;
    const int h0 = blockIdx.y * 64;
    const int c = tid & 63;
    const int r0 = tid >> 6;     // 0..3
#pragma unroll
    for (int it = 0; it < 16; ++it) {
        int r = it * 4 + r0;     // j offset within tile
        lds[r * 65 + c] = bf2f(v[(size_t)(j0 + r) * 3072 + h0 + c]);
    }
    __syncthreads();
    const float rz = 1.0f / z[j0 + c];
#pragma unroll
    for (int it = 0; it < 16; ++it) {
        int r = it * 4 + r0;     // h offset within tile
        vt[(size_t)(h0 + r) * NTOK + j0 + c] = f2bf(lds[c * 65 + r] * rz);
    }
}

// d_out[row] = sum_h logcosh(out[row,h]); bf16 input, one block/row,
// 256 thr x 4 elems (ushort4 = 8B load)
__global__ void logcosh_rowsum(const ushort4* __restrict__ O4,
                               float* __restrict__ out)
{
    const float LN2 = 0.69314718055994531f;
    int row = blockIdx.x;
    ushort4 u = O4[(size_t)row * 256 + threadIdx.x];
    float s = 0.0f, a;
    a = fabsf(bf2f(u.x)); s += a + log1pf(__expf(-2.0f * a));
    a = fabsf(bf2f(u.y)); s += a + log1pf(__expf(-2.0f * a));
    a = fabsf(bf2f(u.z)); s += a + log1pf(__expf(-2.0f * a));
    a = fabsf(bf2f(u.w)); s += a + log1pf(__expf(-2.0f * a));
    s -= 4.0f * LN2;
    for (int off = 32; off; off >>= 1) s += __shfl_down(s, off, 64);
    __shared__ float red[4];
    if ((threadIdx.x & 63) == 0) red[threadIdx.x >> 6] = s;
    __syncthreads();
    if (threadIdx.x == 0) out[row] = red[0] + red[1] + red[2] + red[3];
}

extern "C" void kernel_launch(void* const* d_in, const int* in_sizes, int n_in,
                              void* d_out, int out_size, void* d_ws, size_t ws_size,
                              hipStream_t stream)
{
    (void)in_sizes; (void)n_in; (void)out_size; (void)ws_size;

    const float* x    = (const float*)d_in[0];
    const float* W_in = (const float*)d_in[1];
    const float* b_in = (const float*)d_in[2];
    const float* Wq   = (const float*)d_in[3];
    const float* Wk   = (const float*)d_in[4];
    const float* Wv   = (const float*)d_in[5];
    float* out = (float*)d_out;

    // ---- workspace carve, total ~200 MiB (aliased lifetimes) ----
    char* w = (char*)d_ws;
    const size_t MiB = 1024 * 1024;
    unsigned short* Pb     = (unsigned short*)(w);                 // S->P
    unsigned short* qkv    = (unsigned short*)(w + 128 * MiB);
    unsigned short* xb     = (unsigned short*)(w + 128 * MiB);     // alias
    unsigned short* outb   = (unsigned short*)(w + 128 * MiB);     // alias
    unsigned short* hb     = (unsigned short*)(w + 176 * MiB);
    unsigned short* vtb    = (unsigned short*)(w + 176 * MiB);     // alias hb
    unsigned short* wib    = (unsigned short*)(w + 192 * MiB);
    unsigned short* wqkvb  = (unsigned short*)(w + 194 * MiB);     // [Wq;Wk;Wv]
    float*          pz     = (float*)         (w + 200 * MiB);

    // 1) fp32 -> bf16 converts + pz zero-fill (single launch)
    {
        int n4x = NTOK * NHID / 4;      // 2M float4
        int n4w = NHID * NHID / 4;      // 256K float4 per weight
        int n4  = n4x + 4 * n4w;        // 3M total (divisible by 256)
        cvt_all<<<n4 / 256 + 8, 256, 0, stream>>>(
            (const float4*)x, (const float4*)W_in, (const float4*)Wq,
            (const float4*)Wk, (const float4*)Wv,
            (ushort4*)xb, (ushort4*)wib, (float4*)pz, n4x, n4w);
    }

    // 2) h = x @ W_in^T + b_in   -> bf16 [N,H]   (reads xb, writes hb)
    dim3 gNH(NHID / 128, NTOK / 256);   // (8, 32)
    gemm_bt4<1, false><<<gNH, 512, 0, stream>>>(
        xb, wib, hb, b_in, nullptr, 1.0f, NTOK, NHID, NHID, NHID, NHID);

    // 3) [q|k|v] = h @ [Wq;Wk;Wv]^T -> qkv [N, 3072]  (single fused GEMM)
    dim3 gQKV(3 * NHID / 128, NTOK / 256);  // (24, 32)
    gemm_bt4<1, false><<<gQKV, 512, 0, stream>>>(
        hb, wqkvb, qkv, nullptr, nullptr, 1.0f, NTOK, 3 * NHID, NHID, NHID, NHID);

    // 4) P = exp(0.25 * q @ k^T - 64) -> bf16 [N,N]; fused z_j = sum_i P[i,j]
    //    256x256-tile register-pipelined kernel (grid 32x32 = 1024 blocks)
    dim3 gS(NTOK / 256, NTOK / 256);    // (32, 32)
    gemm_sq2<2, false><<<gS, 512, 0, stream>>>(
        qkv, qkv + NHID, Pb, nullptr, pz, 0.25f, NTOK, NTOK, NHID,
        3 * NHID, 3 * NHID);

    // 5) vtb[h][j] = v[j][h] / z_j   (v = qkv[:,2048:3072], stride 3072)
    dim3 gT(NTOK / 64, NHID / 64);      // (128, 16)
    transpose_scale<<<gT, 256, 0, stream>>>(qkv + 2 * NHID, pz, vtb);

    // 6) out = P @ v'^T -> bf16 [N,H]  (outb aliases dead q region)
    dim3 gO(NTOK / 256, NHID / 128);    // (32, 8) with SWAP mapping
    gemm_bt4<1, true><<<gO, 512, 0, stream>>>(
        Pb, vtb, outb, nullptr, nullptr, 1.0f, NTOK, NHID, NTOK, NTOK, NTOK);

    // 7) d_out[i] = sum_h logcosh(outb[i,h])
    logcosh_rowsum<<<NTOK, 256, 0, stream>>>((const ushort4*)outb, out);
}

// Round 7
// 452.031 us; speedup vs baseline: 1.0777x; 1.0777x over previous
//
#include <hip/hip_runtime.h>
#include <hip/hip_bf16.h>
#include <cstdint>
#include <cstddef>

// Problem constants
#define NTOK 8192   // N
#define NHID 1024   // hidden == n_spins

typedef __attribute__((ext_vector_type(8))) __bf16 bf16x8;
typedef __attribute__((ext_vector_type(4))) float f32x4;

__device__ __forceinline__ unsigned short f2bf(float f) {
    union { float f; unsigned u; } v; v.f = f;
    unsigned r = v.u + 0x7FFF + ((v.u >> 16) & 1);   // RNE
    return (unsigned short)(r >> 16);
}

__device__ __forceinline__ float bf2f(unsigned short u) {
    union { unsigned u; float f; } v; v.u = ((unsigned)u) << 16;
    return v.f;
}

__device__ __forceinline__ void async_copy16(const void* gsrc, void* ldsdst) {
    __builtin_amdgcn_global_load_lds(
        (const __attribute__((address_space(1))) unsigned int*)gsrc,
        (__attribute__((address_space(3))) unsigned int*)ldsdst,
        16, 0, 0);
}

// ---------------------------------------------------------------------------
// R14: gemm_sq3 — faithful m201-style 4-phase-per-K-tile schedule at 256x256.
// R13 post-mortem: mega-burst {12 ds_read -> 32 MFMA} keeps each wave in a
// single-pipe region; barriers lockstep all 8 waves -> CU alternates
// LDS-phase/MFMA-phase (observed 5990 cyc/tile ~= serialized sum; MfmaUtil
// 37%). The verified template's missing feature: FINE phases with quadrant
// register reuse — per phase only 4-8 ds_read feed 16 MFMA; small read
// bursts drain while the matrix pipe finishes the previous phase's MFMAs.
//   ph0 (ks0,ihalf0): read a[0..3](ks0,lo)+b[0..3](ks0) | stage A(t+1)->nb
//   ph1 (ks0,ihalf1): read a[0..3](ks0,hi)              | stage B(t+1)->nb
//   ph2 (ks1,ihalf0): read a(ks1,lo)+b(ks1)
//   ph3 (ks1,ihalf1): read a(ks1,hi); vmcnt(0) at end (loads are >=2 phases
//                     old -> drain is latency-covered), tile-boundary barrier.
// Each phase: {reads||stage} -> s_barrier -> lgkmcnt(0) -> sched_barrier(0)
// (rule #18) -> setprio(1) -> 16 MFMA -> setprio(0) -> s_barrier.
// Buffer safety: stage targets nb; nb's last reads were drained at the
// previous tile's ph3 lgkm0 + boundary barrier. 2 buffers x 64 KiB = 128 KiB.
//
// Epilogue fix (R6 counter evidence): WRITE_SIZE was 309 MB vs 134 MB logical
// — j-outer store order touched each 128-B C-line 4x ~96 stores apart; with
// 32 blocks/XCD streaming, lines evicted partially-dirty between touches.
// Now i,r outer / j inner: the 4 x 32-B chunks of each line are temporally
// adjacent -> single write-back. colsum[4] statically indexed (rule #20).
//
// EPI 0: fp32 store, linear          EPI 1: bf16 store, linear
// EPI 2: bf16 store, exp(scale*acc - 64) + fused column-sum atomicAdd to zsum
// M,N multiples of 256, K multiple of 64.
// ---------------------------------------------------------------------------
template <int EPI, bool SWAP>
__global__ __launch_bounds__(512, 2) void gemm_sq3(
    const unsigned short* __restrict__ A,
    const unsigned short* __restrict__ B,
    void* __restrict__ C,
    const float* __restrict__ bias,
    float* __restrict__ zsum,
    float scale, int M, int N, int K, int lda, int ldb)
{
    // 2 x (A[256][64] | B[256][64]) bf16; A at +0 (16384 ush), B at +16384.
    __shared__ __attribute__((aligned(16))) unsigned short lds[2][32768];

    const int tid  = threadIdx.x;
    const int wave = tid >> 6;          // 0..7
    const int lane = tid & 63;
    const int bm = (SWAP ? blockIdx.x : blockIdx.y) * 256;
    const int bn = (SWAP ? blockIdx.y : blockIdx.x) * 256;
    const size_t ldaz = (size_t)lda;
    const size_t ldbz = (size_t)ldb;

    // staging: LDS rows of 64 bf16 (128 B), chunk XOR-swizzled by row&7 on the
    // global-source side; linear LDS dest (R4-verified pairing).
    const int srow = lane >> 3;
    const int scol = ((lane & 7) ^ srow) * 8;
    const unsigned short* Ag[4];
    const unsigned short* Bg[4];
    int off[4];
#pragma unroll
    for (int t = 0; t < 4; ++t) {
        int r = (wave * 4 + t) * 8 + srow;
        Ag[t] = A + (size_t)(bm + r) * ldaz + scol;
        Bg[t] = B + (size_t)(bn + r) * ldbz + scol;
        off[t] = (wave * 4 + t) * 512;   // wave-uniform; HW adds lane*16B
    }

    // per-wave output placement: 2 M-waves x 4 N-waves, each 128x64
    const int wm = (wave >> 2) * 128;
    const int wn = (wave & 3) * 64;
    const int fr = lane & 15;
    const int frl = fr & 7;
    const int q = lane >> 4;

    const int pc0 = (q ^ frl) * 8;           // swizzled chunk, ks=0
    const int pc1 = ((4 + q) ^ frl) * 8;     // swizzled chunk, ks=1

    f32x4 acc[8][4] = {};

    const int nt = K >> 6;             // BK=64 tiles

    auto stageA = [&](int s) {
#pragma unroll
        for (int t = 0; t < 4; ++t) { async_copy16(Ag[t], &lds[s][off[t]]); Ag[t] += 64; }
    };
    auto stageB = [&](int s) {
#pragma unroll
        for (int t = 0; t < 4; ++t) { async_copy16(Bg[t], &lds[s][16384 + off[t]]); Bg[t] += 64; }
    };

#define PHASE_MFMA(IBASE)                                                      \
    do {                                                                       \
        __builtin_amdgcn_s_setprio(1);                                         \
        _Pragma("unroll")                                                      \
        for (int i = 0; i < 4; ++i)                                            \
            _Pragma("unroll")                                                  \
            for (int j = 0; j < 4; ++j)                                        \
                acc[(IBASE) + i][j] = __builtin_amdgcn_mfma_f32_16x16x32_bf16( \
                    a[i], b[j], acc[(IBASE) + i][j], 0, 0, 0);                 \
        __builtin_amdgcn_s_setprio(0);                                         \
    } while (0)

    // prologue: tile0 -> buf0, full drain (one-time cost)
    stageA(0);
    stageB(0);
    asm volatile("s_waitcnt vmcnt(0)" ::: "memory");
    asm volatile("s_barrier" ::: "memory");

    for (int t = 0; t < nt; ++t) {
        const int cb = t & 1;
        const int nb = cb ^ 1;
        const unsigned short* As = &lds[cb][0];
        const unsigned short* Bs = &lds[cb][16384];
        const bool pf = (t + 1 < nt);   // workgroup-uniform

        bf16x8 a[4], b[4];

        // ===== ph0: ks0, i-half 0; stage A(t+1) =====
#pragma unroll
        for (int i = 0; i < 4; ++i) a[i] = *(const bf16x8*)&As[(wm + i * 16 + fr) * 64 + pc0];
#pragma unroll
        for (int j = 0; j < 4; ++j) b[j] = *(const bf16x8*)&Bs[(wn + j * 16 + fr) * 64 + pc0];
        if (pf) stageA(nb);
        asm volatile("s_barrier" ::: "memory");
        asm volatile("s_waitcnt lgkmcnt(0)" ::: "memory");
        __builtin_amdgcn_sched_barrier(0);
        PHASE_MFMA(0);
        asm volatile("s_barrier" ::: "memory");

        // ===== ph1: ks0, i-half 1; stage B(t+1) =====
#pragma unroll
        for (int i = 0; i < 4; ++i) a[i] = *(const bf16x8*)&As[(wm + 64 + i * 16 + fr) * 64 + pc0];
        if (pf) stageB(nb);
        asm volatile("s_barrier" ::: "memory");
        asm volatile("s_waitcnt lgkmcnt(0)" ::: "memory");
        __builtin_amdgcn_sched_barrier(0);
        PHASE_MFMA(4);
        asm volatile("s_barrier" ::: "memory");

        // ===== ph2: ks1, i-half 0 =====
#pragma unroll
        for (int i = 0; i < 4; ++i) a[i] = *(const bf16x8*)&As[(wm + i * 16 + fr) * 64 + pc1];
#pragma unroll
        for (int j = 0; j < 4; ++j) b[j] = *(const bf16x8*)&Bs[(wn + j * 16 + fr) * 64 + pc1];
        asm volatile("s_barrier" ::: "memory");
        asm volatile("s_waitcnt lgkmcnt(0)" ::: "memory");
        __builtin_amdgcn_sched_barrier(0);
        PHASE_MFMA(0);
        asm volatile("s_barrier" ::: "memory");

        // ===== ph3: ks1, i-half 1; tile-boundary wait =====
#pragma unroll
        for (int i = 0; i < 4; ++i) a[i] = *(const bf16x8*)&As[(wm + 64 + i * 16 + fr) * 64 + pc1];
        asm volatile("s_barrier" ::: "memory");
        asm volatile("s_waitcnt lgkmcnt(0)" ::: "memory");
        __builtin_amdgcn_sched_barrier(0);
        PHASE_MFMA(4);
        if (pf) asm volatile("s_waitcnt vmcnt(0)" ::: "memory");  // t+1 landed
        asm volatile("s_barrier" ::: "memory");
    }
#undef PHASE_MFMA

    // epilogue: D[row=(lane>>4)*4+r][col=lane&15]; i,r OUTER / j INNER so each
    // 128-B C-line's 4 chunks are written temporally adjacent (R6 WRITE fix).
    const int erow = q * 4;
    float colsum[4] = {0.f, 0.f, 0.f, 0.f};
    float bv[4];
#pragma unroll
    for (int j = 0; j < 4; ++j)
        bv[j] = (EPI == 1 && bias) ? bias[bn + wn + j * 16 + fr] : 0.0f;
#pragma unroll
    for (int i = 0; i < 8; ++i) {
        const int grow0 = bm + wm + i * 16 + erow;
#pragma unroll
        for (int r = 0; r < 4; ++r) {
            const size_t rowoff = (size_t)(grow0 + r) * N;
#pragma unroll
            for (int j = 0; j < 4; ++j) {
                const int gcol = bn + wn + j * 16 + fr;
                float v;
                if (EPI == 2) {
                    // P = exp(scale*acc - 64): fixed-shift softmax numerator.
                    v = __expf(fmaf(acc[i][j][r], scale, -64.0f));
                    colsum[j] += v;
                } else {
                    v = acc[i][j][r] * scale + bv[j];
                }
                if (EPI == 0) ((float*)C)[rowoff + gcol] = v;
                else          ((unsigned short*)C)[rowoff + gcol] = f2bf(v);
            }
        }
    }
    if (EPI == 2) {
#pragma unroll
        for (int j = 0; j < 4; ++j) {
            float cs = colsum[j];
            cs += __shfl_xor(cs, 16, 64);
            cs += __shfl_xor(cs, 32, 64);
            if (q == 0) atomicAdd(&zsum[bn + wn + j * 16 + fr], cs);
        }
    }
}

// ---------------------------------------------------------------------------
// gemm_bt4 (R11): 256x128 tile, cross-phase register pipelining — kept for
// the GEMMs whose N is too small for 256-wide tiles (h, qkv, attn@v).
// ---------------------------------------------------------------------------
template <int EPI, bool SWAP>
__global__ __launch_bounds__(512, 2) void gemm_bt4(
    const unsigned short* __restrict__ A,
    const unsigned short* __restrict__ B,
    void* __restrict__ C,
    const float* __restrict__ bias,
    float* __restrict__ zsum,
    float scale, int M, int N, int K, int lda, int ldb)
{
    __shared__ __attribute__((aligned(16))) unsigned short lds[3][24576];

    const int tid  = threadIdx.x;
    const int wave = tid >> 6;          // 0..7
    const int lane = tid & 63;
    const int bm = (SWAP ? blockIdx.x : blockIdx.y) * 256;
    const int bn = (SWAP ? blockIdx.y : blockIdx.x) * 128;
    const size_t ldaz = (size_t)lda;
    const size_t ldbz = (size_t)ldb;

    const int srow = lane >> 3;
    const int scol = ((lane & 7) ^ srow) * 8;
    const unsigned short* Ag[4];
    const unsigned short* Bg[2];
    int Aoff[4], Boff[2];
#pragma unroll
    for (int t = 0; t < 4; ++t) {
        int r = (wave * 4 + t) * 8 + srow;
        Ag[t] = A + (size_t)(bm + r) * ldaz + scol;
        Aoff[t] = (wave * 4 + t) * 512;
    }
#pragma unroll
    for (int t = 0; t < 2; ++t) {
        int r = (wave * 2 + t) * 8 + srow;
        Bg[t] = B + (size_t)(bn + r) * ldbz + scol;
        Boff[t] = 16384 + (wave * 2 + t) * 512;
    }

    const int wm = (wave >> 1) * 64;
    const int wn = (wave & 1) * 64;
    const int fr = lane & 15;
    const int frl = fr & 7;
    const int q = lane >> 4;

    const int pc0 = (q ^ frl) * 8;
    const int pc1 = ((4 + q) ^ frl) * 8;

    f32x4 acc[4][4] = {};

    const int nt = K >> 6;

    {
        unsigned short* b0 = &lds[0][0];
        unsigned short* b1 = &lds[1][0];
#pragma unroll
        for (int u = 0; u < 4; ++u) { async_copy16(Ag[u], b0 + Aoff[u]); Ag[u] += 64; }
#pragma unroll
        for (int u = 0; u < 2; ++u) { async_copy16(Bg[u], b0 + Boff[u]); Bg[u] += 64; }
#pragma unroll
        for (int u = 0; u < 4; ++u) { async_copy16(Ag[u], b1 + Aoff[u]); Ag[u] += 64; }
#pragma unroll
        for (int u = 0; u < 2; ++u) { async_copy16(Bg[u], b1 + Boff[u]); Bg[u] += 64; }
        asm volatile("s_waitcnt vmcnt(6)" ::: "memory");
        asm volatile("s_barrier" ::: "memory");
    }

    bf16x8 a0_0, a0_1, a0_2, a0_3, b0_0, b0_1, b0_2, b0_3;   // SET0
    bf16x8 a1_0, a1_1, a1_2, a1_3, b1_0, b1_1, b1_2, b1_3;   // SET1

    {
        const unsigned short* As = &lds[0][0];
        const unsigned short* Bs = &lds[0][16384];
        a0_0 = *(const bf16x8*)&As[(wm +  0 + fr) * 64 + pc0];
        a0_1 = *(const bf16x8*)&As[(wm + 16 + fr) * 64 + pc0];
        a0_2 = *(const bf16x8*)&As[(wm + 32 + fr) * 64 + pc0];
        a0_3 = *(const bf16x8*)&As[(wm + 48 + fr) * 64 + pc0];
        b0_0 = *(const bf16x8*)&Bs[(wn +  0 + fr) * 64 + pc0];
        b0_1 = *(const bf16x8*)&Bs[(wn + 16 + fr) * 64 + pc0];
        b0_2 = *(const bf16x8*)&Bs[(wn + 32 + fr) * 64 + pc0];
        b0_3 = *(const bf16x8*)&Bs[(wn + 48 + fr) * 64 + pc0];
    }

#define MFMA16(AA0, AA1, AA2, AA3, BB0, BB1, BB2, BB3)                         \
    do {                                                                       \
        __builtin_amdgcn_s_setprio(1);                                         \
        acc[0][0] = __builtin_amdgcn_mfma_f32_16x16x32_bf16(AA0, BB0, acc[0][0], 0, 0, 0); \
        acc[0][1] = __builtin_amdgcn_mfma_f32_16x16x32_bf16(AA0, BB1, acc[0][1], 0, 0, 0); \
        acc[0][2] = __builtin_amdgcn_mfma_f32_16x16x32_bf16(AA0, BB2, acc[0][2], 0, 0, 0); \
        acc[0][3] = __builtin_amdgcn_mfma_f32_16x16x32_bf16(AA0, BB3, acc[0][3], 0, 0, 0); \
        acc[1][0] = __builtin_amdgcn_mfma_f32_16x16x32_bf16(AA1, BB0, acc[1][0], 0, 0, 0); \
        acc[1][1] = __builtin_amdgcn_mfma_f32_16x16x32_bf16(AA1, BB1, acc[1][1], 0, 0, 0); \
        acc[1][2] = __builtin_amdgcn_mfma_f32_16x16x32_bf16(AA1, BB2, acc[1][2], 0, 0, 0); \
        acc[1][3] = __builtin_amdgcn_mfma_f32_16x16x32_bf16(AA1, BB3, acc[1][3], 0, 0, 0); \
        acc[2][0] = __builtin_amdgcn_mfma_f32_16x16x32_bf16(AA2, BB0, acc[2][0], 0, 0, 0); \
        acc[2][1] = __builtin_amdgcn_mfma_f32_16x16x32_bf16(AA2, BB1, acc[2][1], 0, 0, 0); \
        acc[2][2] = __builtin_amdgcn_mfma_f32_16x16x32_bf16(AA2, BB2, acc[2][2], 0, 0, 0); \
        acc[2][3] = __builtin_amdgcn_mfma_f32_16x16x32_bf16(AA2, BB3, acc[2][3], 0, 0, 0); \
        acc[3][0] = __builtin_amdgcn_mfma_f32_16x16x32_bf16(AA3, BB0, acc[3][0], 0, 0, 0); \
        acc[3][1] = __builtin_amdgcn_mfma_f32_16x16x32_bf16(AA3, BB1, acc[3][1], 0, 0, 0); \
        acc[3][2] = __builtin_amdgcn_mfma_f32_16x16x32_bf16(AA3, BB2, acc[3][2], 0, 0, 0); \
        acc[3][3] = __builtin_amdgcn_mfma_f32_16x16x32_bf16(AA3, BB3, acc[3][3], 0, 0, 0); \
        __builtin_amdgcn_s_setprio(0);                                         \
    } while (0)

    int cb = 0;
    int sb = 2;
    for (int t = 0; t < nt; ++t) {
        const bool pf = (t + 2 < nt);
        const unsigned short* As = &lds[cb][0];
        const unsigned short* Bs = &lds[cb][16384];
        unsigned short* Sb = &lds[sb][0];
        const int nb = (cb == 2) ? 0 : cb + 1;
        const unsigned short* An = &lds[nb][0];
        const unsigned short* Bn = &lds[nb][16384];

        a1_0 = *(const bf16x8*)&As[(wm +  0 + fr) * 64 + pc1];
        a1_1 = *(const bf16x8*)&As[(wm + 16 + fr) * 64 + pc1];
        a1_2 = *(const bf16x8*)&As[(wm + 32 + fr) * 64 + pc1];
        a1_3 = *(const bf16x8*)&As[(wm + 48 + fr) * 64 + pc1];
        b1_0 = *(const bf16x8*)&Bs[(wn +  0 + fr) * 64 + pc1];
        b1_1 = *(const bf16x8*)&Bs[(wn + 16 + fr) * 64 + pc1];
        b1_2 = *(const bf16x8*)&Bs[(wn + 32 + fr) * 64 + pc1];
        b1_3 = *(const bf16x8*)&Bs[(wn + 48 + fr) * 64 + pc1];
        if (pf) {
#pragma unroll
            for (int u = 0; u < 4; ++u) { async_copy16(Ag[u], Sb + Aoff[u]); Ag[u] += 64; }
        }
        __builtin_amdgcn_sched_barrier(0);
        MFMA16(a0_0, a0_1, a0_2, a0_3, b0_0, b0_1, b0_2, b0_3);
        if (t < nt - 2) asm volatile("s_waitcnt vmcnt(4)" ::: "memory");
        else            asm volatile("s_waitcnt vmcnt(0)" ::: "memory");
        asm volatile("s_barrier" ::: "memory");

        if (t + 1 < nt) {
            a0_0 = *(const bf16x8*)&An[(wm +  0 + fr) * 64 + pc0];
            a0_1 = *(const bf16x8*)&An[(wm + 16 + fr) * 64 + pc0];
            a0_2 = *(const bf16x8*)&An[(wm + 32 + fr) * 64 + pc0];
            a0_3 = *(const bf16x8*)&An[(wm + 48 + fr) * 64 + pc0];
            b0_0 = *(const bf16x8*)&Bn[(wn +  0 + fr) * 64 + pc0];
            b0_1 = *(const bf16x8*)&Bn[(wn + 16 + fr) * 64 + pc0];
            b0_2 = *(const bf16x8*)&Bn[(wn + 32 + fr) * 64 + pc0];
            b0_3 = *(const bf16x8*)&Bn[(wn + 48 + fr) * 64 + pc0];
        }
        if (pf) {
#pragma unroll
            for (int u = 0; u < 2; ++u) { async_copy16(Bg[u], Sb + Boff[u]); Bg[u] += 64; }
        }
        __builtin_amdgcn_sched_barrier(0);
        MFMA16(a1_0, a1_1, a1_2, a1_3, b1_0, b1_1, b1_2, b1_3);
        asm volatile("s_barrier" ::: "memory");

        if (pf) sb = (sb == 2) ? 0 : sb + 1;
        cb = nb;
    }
#undef MFMA16

    const int erow = q * 4;
#pragma unroll
    for (int j = 0; j < 4; ++j) {
        const int gcol = bn + wn + j * 16 + fr;
        const float bv = (EPI == 1 && bias) ? bias[gcol] : 0.0f;
        float colsum = 0.0f;
#pragma unroll
        for (int i = 0; i < 4; ++i) {
            const int grow0 = bm + wm + i * 16 + erow;
#pragma unroll
            for (int r = 0; r < 4; ++r) {
                float v;
                if (EPI == 2) {
                    v = __expf(fmaf(acc[i][j][r], scale, -64.0f));
                    colsum += v;
                } else {
                    v = acc[i][j][r] * scale + bv;
                }
                size_t idx = (size_t)(grow0 + r) * N + gcol;
                if (EPI == 0) ((float*)C)[idx] = v;
                else          ((unsigned short*)C)[idx] = f2bf(v);
            }
        }
        if (EPI == 2) {
            colsum += __shfl_xor(colsum, 16, 64);
            colsum += __shfl_xor(colsum, 32, 64);
            if (q == 0) atomicAdd(&zsum[gcol], colsum);
        }
    }
}

// fused fp32->bf16 convert for x (n4x float4s) + 4 weight mats (n4w each)
// into xb and the CONTIGUOUS weight region wdst (wib|wq|wk|wv).
// Extra 8 trailing blocks zero-fill pz (2048 float4 = 8192 floats).
__global__ void cvt_all(const float4* __restrict__ x,
                        const float4* __restrict__ w0,
                        const float4* __restrict__ w1,
                        const float4* __restrict__ w2,
                        const float4* __restrict__ w3,
                        ushort4* __restrict__ xb,
                        ushort4* __restrict__ wdst,
                        float4* __restrict__ pz4,
                        int n4x, int n4w)
{
    int i = blockIdx.x * blockDim.x + threadIdx.x;
    int n4 = n4x + 4 * n4w;
    if (i >= n4) {
        int zi = i - n4;
        if (zi < 2048) pz4[zi] = make_float4(0.f, 0.f, 0.f, 0.f);
        return;
    }
    float4 f;
    ushort4* dst;
    if (i < n4x) {
        f = x[i]; dst = xb + i;
    } else {
        int r = i - n4x;
        int seg = r / n4w, off = r % n4w;
        const float4* src = (seg == 0) ? w0 : (seg == 1) ? w1 : (seg == 2) ? w2 : w3;
        f = src[off]; dst = wdst + r;
    }
    ushort4 o;
    o.x = f2bf(f.x); o.y = f2bf(f.y); o.z = f2bf(f.z); o.w = f2bf(f.w);
    *dst = o;
}

// vt[h][j] = v[j][h] / z[j]; v is a [NTOK, NHID] view with row stride 3072
// (the v slice of qkv). 64x64 tile via float LDS (stride 65). Both global
// sides coalesced (128B/wave segments).
__global__ __launch_bounds__(256) void transpose_scale(
    const unsigned short* __restrict__ v,
    const float* __restrict__ z,
    unsigned short* __restrict__ vt)
{
    __shared__ float lds[64 * 65];
    const int tid = threadIdx.x;
    const int j0 = blockIdx.x * 64;
    const int h0 = blockIdx.y * 64;
    const int c = tid & 63;
    const int r0 = tid >> 6;     // 0..3
#pragma unroll
    for (int it = 0; it < 16; ++it) {
        int r = it * 4 + r0;     // j offset within tile
        lds[r * 65 + c] = bf2f(v[(size_t)(j0 + r) * 3072 + h0 + c]);
    }
    __syncthreads();
    const float rz = 1.0f / z[j0 + c];
#pragma unroll
    for (int it = 0; it < 16; ++it) {
        int r = it * 4 + r0;     // h offset within tile
        vt[(size_t)(h0 + r) * NTOK + j0 + c] = f2bf(lds[c * 65 + r] * rz);
    }
}

// d_out[row] = sum_h logcosh(out[row,h]); bf16 input, one block/row,
// 256 thr x 4 elems (ushort4 = 8B load)
__global__ void logcosh_rowsum(const ushort4* __restrict__ O4,
                               float* __restrict__ out)
{
    const float LN2 = 0.69314718055994531f;
    int row = blockIdx.x;
    ushort4 u = O4[(size_t)row * 256 + threadIdx.x];
    float s = 0.0f, a;
    a = fabsf(bf2f(u.x)); s += a + log1pf(__expf(-2.0f * a));
    a = fabsf(bf2f(u.y)); s += a + log1pf(__expf(-2.0f * a));
    a = fabsf(bf2f(u.z)); s += a + log1pf(__expf(-2.0f * a));
    a = fabsf(bf2f(u.w)); s += a + log1pf(__expf(-2.0f * a));
    s -= 4.0f * LN2;
    for (int off = 32; off; off >>= 1) s += __shfl_down(s, off, 64);
    __shared__ float red[4];
    if ((threadIdx.x & 63) == 0) red[threadIdx.x >> 6] = s;
    __syncthreads();
    if (threadIdx.x == 0) out[row] = red[0] + red[1] + red[2] + red[3];
}

extern "C" void kernel_launch(void* const* d_in, const int* in_sizes, int n_in,
                              void* d_out, int out_size, void* d_ws, size_t ws_size,
                              hipStream_t stream)
{
    (void)in_sizes; (void)n_in; (void)out_size; (void)ws_size;

    const float* x    = (const float*)d_in[0];
    const float* W_in = (const float*)d_in[1];
    const float* b_in = (const float*)d_in[2];
    const float* Wq   = (const float*)d_in[3];
    const float* Wk   = (const float*)d_in[4];
    const float* Wv   = (const float*)d_in[5];
    float* out = (float*)d_out;

    // ---- workspace carve, total ~200 MiB (aliased lifetimes) ----
    char* w = (char*)d_ws;
    const size_t MiB = 1024 * 1024;
    unsigned short* Pb     = (unsigned short*)(w);                 // S->P
    unsigned short* qkv    = (unsigned short*)(w + 128 * MiB);
    unsigned short* xb     = (unsigned short*)(w + 128 * MiB);     // alias
    unsigned short* outb   = (unsigned short*)(w + 128 * MiB);     // alias
    unsigned short* hb     = (unsigned short*)(w + 176 * MiB);
    unsigned short* vtb    = (unsigned short*)(w + 176 * MiB);     // alias hb
    unsigned short* wib    = (unsigned short*)(w + 192 * MiB);
    unsigned short* wqkvb  = (unsigned short*)(w + 194 * MiB);     // [Wq;Wk;Wv]
    float*          pz     = (float*)         (w + 200 * MiB);

    // 1) fp32 -> bf16 converts + pz zero-fill (single launch)
    {
        int n4x = NTOK * NHID / 4;      // 2M float4
        int n4w = NHID * NHID / 4;      // 256K float4 per weight
        int n4  = n4x + 4 * n4w;        // 3M total (divisible by 256)
        cvt_all<<<n4 / 256 + 8, 256, 0, stream>>>(
            (const float4*)x, (const float4*)W_in, (const float4*)Wq,
            (const float4*)Wk, (const float4*)Wv,
            (ushort4*)xb, (ushort4*)wib, (float4*)pz, n4x, n4w);
    }

    // 2) h = x @ W_in^T + b_in   -> bf16 [N,H]   (reads xb, writes hb)
    dim3 gNH(NHID / 128, NTOK / 256);   // (8, 32)
    gemm_bt4<1, false><<<gNH, 512, 0, stream>>>(
        xb, wib, hb, b_in, nullptr, 1.0f, NTOK, NHID, NHID, NHID, NHID);

    // 3) [q|k|v] = h @ [Wq;Wk;Wv]^T -> qkv [N, 3072]  (single fused GEMM)
    dim3 gQKV(3 * NHID / 128, NTOK / 256);  // (24, 32)
    gemm_bt4<1, false><<<gQKV, 512, 0, stream>>>(
        hb, wqkvb, qkv, nullptr, nullptr, 1.0f, NTOK, 3 * NHID, NHID, NHID, NHID);

    // 4) P = exp(0.25 * q @ k^T - 64) -> bf16 [N,N]; fused z_j = sum_i P[i,j]
    //    4-phase fine-interleave kernel (grid 32x32 = 1024 blocks)
    dim3 gS(NTOK / 256, NTOK / 256);    // (32, 32)
    gemm_sq3<2, false><<<gS, 512, 0, stream>>>(
        qkv, qkv + NHID, Pb, nullptr, pz, 0.25f, NTOK, NTOK, NHID,
        3 * NHID, 3 * NHID);

    // 5) vtb[h][j] = v[j][h] / z_j   (v = qkv[:,2048:3072], stride 3072)
    dim3 gT(NTOK / 64, NHID / 64);      // (128, 16)
    transpose_scale<<<gT, 256, 0, stream>>>(qkv + 2 * NHID, pz, vtb);

    // 6) out = P @ v'^T -> bf16 [N,H]  (outb aliases dead q region)
    dim3 gO(NTOK / 256, NHID / 128);    // (32, 8) with SWAP mapping
    gemm_bt4<1, true><<<gO, 512, 0, stream>>>(
        Pb, vtb, outb, nullptr, nullptr, 1.0f, NTOK, NHID, NTOK, NTOK, NTOK);

    // 7) d_out[i] = sum_h logcosh(outb[i,h])
    logcosh_rowsum<<<NTOK, 256, 0, stream>>>((const ushort4*)outb, out);
}